// Round 4
// baseline (284.379 us; speedup 1.0000x reference)
//
#include <hip/hip_runtime.h>
#include <hip/hip_bf16.h>

#define BB 16
#define NN 1024
#define HH 768
#define NEG_INF_ -9.0e15f
#define SLOPE_ 0.2f

typedef __bf16 bh8 __attribute__((ext_vector_type(8)));
typedef __bf16 bh4 __attribute__((ext_vector_type(4)));
typedef float f4 __attribute__((ext_vector_type(4)));
typedef unsigned int u32;

// ---------------- wave-level reductions ----------------

__device__ __forceinline__ float wave_sum0(float v) {       // result valid in lane 0
    #pragma unroll
    for (int off = 32; off > 0; off >>= 1) v += __shfl_down(v, off, 64);
    return v;
}
__device__ __forceinline__ float wave_sum_all(float v) {
    #pragma unroll
    for (int off = 1; off < 64; off <<= 1) v += __shfl_xor(v, off, 64);
    return v;
}
__device__ __forceinline__ float wave_max_all(float v) {
    #pragma unroll
    for (int off = 1; off < 64; off <<= 1) v = fmaxf(v, __shfl_xor(v, off, 64));
    return v;
}

// ---------------- async global->LDS 16B ----------------

__device__ __forceinline__ void gl_lds16(const void* g, void* l) {
    __builtin_amdgcn_global_load_lds(
        (const __attribute__((address_space(1))) u32*)g,
        (__attribute__((address_space(3))) u32*)l, 16, 0, 0);
}

// ---------------- kernel 1: wa = W @ a1|a2 (one wave per f) + zero-init t ----------------
// grid 192 x 256

__global__ __launch_bounds__(256) void wa_kernel(const float* __restrict__ W,
                                                 const float* __restrict__ a,
                                                 float* __restrict__ wa1,
                                                 float* __restrict__ wa2,
                                                 float* __restrict__ t1,
                                                 float* __restrict__ t2) {
    const int gid = blockIdx.x * 256 + threadIdx.x;
    if (gid < BB * NN) { t1[gid] = 0.f; t2[gid] = 0.f; }   // d_ws is poisoned; xt accumulates

    const int f = blockIdx.x * 4 + (threadIdx.x >> 6);
    const int lane = threadIdx.x & 63;
    const float* Wr = W + (size_t)f * HH;
    float v1 = 0.f, v2 = 0.f;
    #pragma unroll
    for (int i = 0; i < 3; i++) {
        const int h = lane * 4 + i * 256;
        const float4 w  = *(const float4*)(Wr + h);
        const float4 a1 = *(const float4*)(a + h);
        const float4 a2 = *(const float4*)(a + HH + h);
        v1 += w.x * a1.x + w.y * a1.y + w.z * a1.z + w.w * a1.w;
        v2 += w.x * a2.x + w.y * a2.y + w.z * a2.z + w.w * a2.w;
    }
    v1 = wave_sum0(v1);
    v2 = wave_sum0(v2);
    if (lane == 0) { wa1[f] = v1; wa2[f] = v2; }
}

// ---------------- kernel 2: xT transpose (f32->bf16) FUSED with t partial dots ----------------
// grid (24 htiles, 32 ntiles, BB) x 256; 32x32 tiles

__global__ __launch_bounds__(256) void xt_kernel(const float* __restrict__ x,
                                                 const float* __restrict__ wa1,
                                                 const float* __restrict__ wa2,
                                                 __bf16* __restrict__ xT,
                                                 float* __restrict__ t1,
                                                 float* __restrict__ t2) {
    __shared__ __bf16 T[32][36];
    const int b = blockIdx.z, nt = blockIdx.y, ht = blockIdx.x;
    const int t = threadIdx.x;
    const int r = t >> 3;          // n within tile (0..31)
    const int c = (t & 7) * 4;     // h within tile (0..28)
    const float4 v = *(const float4*)(x + ((size_t)b * NN + nt * 32 + r) * HH + ht * 32 + c);
    T[r][c + 0] = (__bf16)v.x; T[r][c + 1] = (__bf16)v.y;
    T[r][c + 2] = (__bf16)v.z; T[r][c + 3] = (__bf16)v.w;

    // t partial: dot of this row-segment with wa (wa is 3KB -> L1/L2 resident)
    const float4 w1 = *(const float4*)(wa1 + ht * 32 + c);
    const float4 w2 = *(const float4*)(wa2 + ht * 32 + c);
    float p1 = v.x * w1.x + v.y * w1.y + v.z * w1.z + v.w * w1.w;
    float p2 = v.x * w2.x + v.y * w2.y + v.z * w2.z + v.w * w2.w;
    // 8 threads per row are consecutive lanes -> width-8 shuffle reduce
    p1 += __shfl_down(p1, 4, 8); p1 += __shfl_down(p1, 2, 8); p1 += __shfl_down(p1, 1, 8);
    p2 += __shfl_down(p2, 4, 8); p2 += __shfl_down(p2, 2, 8); p2 += __shfl_down(p2, 1, 8);
    if ((t & 7) == 0) {
        atomicAdd(&t1[b * NN + nt * 32 + r], p1);
        atomicAdd(&t2[b * NN + nt * 32 + r], p2);
    }

    __syncthreads();
    const int h = t >> 3;          // h within tile
    const int nc = (t & 7) * 4;    // n within tile
    bh4 o = { T[nc + 0][h], T[nc + 1][h], T[nc + 2][h], T[nc + 3][h] };
    *(bh4*)(xT + ((size_t)b * HH + ht * 32 + h) * NN + nt * 32 + nc) = o;
}

// ---------------- kernel 3: s = adj·t + adj->bf16 (exact 0/1) ----------------
// grid 4096 x 256 (one wave per row)

__global__ __launch_bounds__(256) void s_pack_kernel(const float* __restrict__ adj,
                                                     const float* __restrict__ t1,
                                                     const float* __restrict__ t2,
                                                     float* __restrict__ s1,
                                                     float* __restrict__ s2,
                                                     __bf16* __restrict__ adjB) {
    const int row = blockIdx.x * 4 + (threadIdx.x >> 6);
    const int lane = threadIdx.x & 63;
    const int b = row >> 10;
    const float* ar = adj + (size_t)row * NN;
    __bf16* abr = adjB + (size_t)row * NN;
    const float* t1b = t1 + b * NN;
    const float* t2b = t2 + b * NN;
    float v1 = 0.f, v2 = 0.f;
    #pragma unroll
    for (int i = 0; i < 4; i++) {
        const int j = lane * 4 + i * 256;
        const float4 av = *(const float4*)(ar + j);
        const float4 u  = *(const float4*)(t1b + j);
        const float4 w  = *(const float4*)(t2b + j);
        v1 += av.x * u.x + av.y * u.y + av.z * u.z + av.w * u.w;
        v2 += av.x * w.x + av.y * w.y + av.z * w.z + av.w * w.w;
        bh4 o = { (__bf16)av.x, (__bf16)av.y, (__bf16)av.z, (__bf16)av.w };  // 0/1 exact
        *(bh4*)(abr + j) = o;
    }
    v1 = wave_sum0(v1);
    v2 = wave_sum0(v2);
    if (lane == 0) { s1[row] = v1; s2[row] = v2; }
}

// ---------------- kernel 4: node_vec = adjB @ xT^T, m97-style bf16 MFMA GEMM ----------------
// grid (6,8,BB) x 256; 128x128 tile, BK=32, both operands via global_load_lds x16

__global__ __launch_bounds__(256) void gemm_bf16(const __bf16* __restrict__ adjB,
                                                 const __bf16* __restrict__ xT,
                                                 float* __restrict__ out) {
    __shared__ __bf16 As[128 * 32];   // 8 KB, unpadded (global_load_lds layout)
    __shared__ __bf16 Bs[128 * 32];   // 8 KB
    const int b = blockIdx.z, bm = blockIdx.y, bn = blockIdx.x;
    const int tid = threadIdx.x, lane = tid & 63, wave = tid >> 6;
    const int wr = (wave >> 1) << 6;
    const int wc = (wave & 1) << 6;
    const int quad = lane >> 4, l16 = lane & 15;

    const __bf16* Ab = adjB + ((size_t)b * NN + bm * 128) * NN;
    const __bf16* Xb = xT + ((size_t)b * HH + bn * 128) * NN;

    f4 acc[4][4];
    #pragma unroll
    for (int i = 0; i < 4; i++)
        #pragma unroll
        for (int j = 0; j < 4; j++)
            acc[i][j] = (f4){0.f, 0.f, 0.f, 0.f};

    for (int kt = 0; kt < NN; kt += 32) {
        #pragma unroll
        for (int it = 0; it < 2; it++) {
            const int c = tid + 256 * it;       // 512 16B-chunks per tile
            const int r = c >> 2, ko = (c & 3) * 8;
            gl_lds16(Ab + (size_t)r * NN + kt + ko, &As[r * 32 + ko]);
            gl_lds16(Xb + (size_t)r * NN + kt + ko, &Bs[r * 32 + ko]);
        }
        __syncthreads();   // drains vmcnt(0): tiles ready

        bh8 af[4], bf_[4];
        #pragma unroll
        for (int i = 0; i < 4; i++)
            af[i] = *(const bh8*)&As[(wr + i * 16 + l16) * 32 + quad * 8];
        #pragma unroll
        for (int j = 0; j < 4; j++)
            bf_[j] = *(const bh8*)&Bs[(wc + j * 16 + l16) * 32 + quad * 8];

        #pragma unroll
        for (int i = 0; i < 4; i++)
            #pragma unroll
            for (int j = 0; j < 4; j++)
                acc[i][j] = __builtin_amdgcn_mfma_f32_16x16x32_bf16(af[i], bf_[j], acc[i][j], 0, 0, 0);
        __syncthreads();   // reads done before next staging overwrites
    }

    // epilogue: C/D layout col = lane&15, row = (lane>>4)*4 + reg  [m89-verified]
    float* Cb = out + (size_t)b * NN * HH + (size_t)bm * 128 * HH + bn * 128;
    const int rbase = wr + quad * 4;
    const int cbase = wc + l16;
    #pragma unroll
    for (int i = 0; i < 4; i++)
        #pragma unroll
        for (int j = 0; j < 4; j++)
            #pragma unroll
            for (int r = 0; r < 4; r++)
                Cb[(size_t)(rbase + i * 16 + r) * HH + cbase + j * 16] = acc[i][j][r];
}

// ---------------- kernel 5: softmax -- one wave per row, mask from adj (no race) ----------------
// grid 4096 x 256

__global__ __launch_bounds__(256) void softmax_kernel(const float* __restrict__ adj,
                                                      const float* __restrict__ nl,
                                                      const float* __restrict__ s1,
                                                      const float* __restrict__ s2,
                                                      float* __restrict__ attn) {
    const int row = blockIdx.x * 4 + (threadIdx.x >> 6);
    const int lane = threadIdx.x & 63;
    const int b = row >> 10, n = row & (NN - 1);
    const float* ar = adj + (size_t)row * NN;
    const float* nlb = nl + (size_t)b * NN;
    const float* s2b = s2 + (size_t)b * NN;
    const float s1v = s1[row];
    const bool rowok = nlb[n] > 1e-6f;

    f4 sc[4];
    float mx = NEG_INF_;
    #pragma unroll
    for (int i = 0; i < 4; i++) {
        const int j = lane * 4 + i * 256;
        const float4 av = *(const float4*)(ar + j);
        const float4 sv = *(const float4*)(s2b + j);
        const float4 nv = *(const float4*)(nlb + j);
        const float zs[4] = { s1v + sv.x, s1v + sv.y, s1v + sv.z, s1v + sv.w };
        const float as_[4] = { av.x, av.y, av.z, av.w };
        const float ns[4] = { nv.x, nv.y, nv.z, nv.w };
        #pragma unroll
        for (int e = 0; e < 4; e++) {
            const float z = zs[e];
            const float lr = z > 0.f ? z : SLOPE_ * z;
            const bool valid = rowok && (as_[e] > 1e-6f) && (ns[e] > 1e-6f);
            sc[i][e] = valid ? lr : NEG_INF_;
            mx = fmaxf(mx, sc[i][e]);
        }
    }
    mx = wave_max_all(mx);

    f4 ex[4];
    float sum = 0.f;
    #pragma unroll
    for (int i = 0; i < 4; i++)
        #pragma unroll
        for (int e = 0; e < 4; e++) {
            ex[i][e] = __expf(sc[i][e] - mx);   // all-masked row -> uniform, matches JAX
            sum += ex[i][e];
        }
    sum = wave_sum_all(sum);
    const float inv = 1.0f / sum;

    float* outr = attn + (size_t)row * NN;
    #pragma unroll
    for (int i = 0; i < 4; i++) {
        const int j = lane * 4 + i * 256;
        float4 o;
        o.x = ex[i][0] * inv; o.y = ex[i][1] * inv;
        o.z = ex[i][2] * inv; o.w = ex[i][3] * inv;
        *(float4*)(outr + j) = o;
    }
}

// ---------------- launch ----------------

extern "C" void kernel_launch(void* const* d_in, const int* in_sizes, int n_in,
                              void* d_out, int out_size, void* d_ws, size_t ws_size,
                              hipStream_t stream) {
    const float* x   = (const float*)d_in[0];   // (16,1024,768)
    const float* nl  = (const float*)d_in[1];   // (16,1024)
    const float* adj = (const float*)d_in[2];   // (16,1024,1024)
    const float* W   = (const float*)d_in[3];   // (768,768)
    const float* a   = (const float*)d_in[4];   // (1536,1)

    float* out = (float*)d_out;
    float* node_vec = out;                               // 16*1024*768 floats
    float* attn = out + (size_t)BB * NN * HH;            // 16*1024*1024 floats

    // big scratch lives in the attn region; ALL of it is consumed by gemm_bf16,
    // which completes (stream order) before softmax starts writing attn:
    __bf16* xT   = (__bf16*)attn;                        // 24 MB  (B,H,N) bf16
    __bf16* adjB = (__bf16*)(attn + 6291456);            // 32 MB  adj as bf16 (exact)

    float* ws  = (float*)d_ws;                           // small scratch
    float* wa1 = ws;
    float* wa2 = wa1 + HH;
    float* t1  = wa2 + HH;
    float* t2  = t1 + BB * NN;
    float* s1  = t2 + BB * NN;
    float* s2  = s1 + BB * NN;

    hipLaunchKernelGGL(wa_kernel, dim3(192), dim3(256), 0, stream, W, a, wa1, wa2, t1, t2);
    hipLaunchKernelGGL(xt_kernel, dim3(24, 32, BB), dim3(256), 0, stream, x, wa1, wa2, xT, t1, t2);
    hipLaunchKernelGGL(s_pack_kernel, dim3(4096), dim3(256), 0, stream, adj, t1, t2, s1, s2, adjB);
    hipLaunchKernelGGL(gemm_bf16, dim3(6, 8, BB), dim3(256), 0, stream, adjB, xT, node_vec);
    hipLaunchKernelGGL(softmax_kernel, dim3(4096), dim3(256), 0, stream, adj, nl, s1, s2, attn);
}